// Round 18
// baseline (93.902 us; speedup 1.0000x reference)
//
#include <hip/hip_runtime.h>
#include <hip/hip_fp16.h>

#define T1 512
#define NB 32      // batches
#define NP 96      // 3 pairs * 32 batches
#define DHEAD 64

#define RSLOTS 152                 // LDS ring slots (1 KB column each) = 155648 B
#define RBYTES (RSLOTS * 1024)     // 8192*19: stepping by 8192 wraps exactly
#define PFD 30                     // producer prefetch distance (columns ahead)

typedef __attribute__((ext_vector_type(8))) short bf16x8;
typedef __attribute__((ext_vector_type(4))) float f32x4;
typedef __attribute__((ext_vector_type(4))) unsigned int u32x4;

// ---------------- kernel 1: row-normalize x,y -> bf16 ----------------
__global__ __launch_bounds__(256) void k_normalize(const float* __restrict__ x,
                                                   const float* __restrict__ y,
                                                   ushort* __restrict__ xb,
                                                   ushort* __restrict__ yb) {
  int wid  = threadIdx.x >> 6;
  int lane = threadIdx.x & 63;
  int row  = blockIdx.x * 4 + wid;          // 0 .. 32767
  const float* src; ushort* dst;
  if (row < NB * T1) { src = x + (size_t)row * DHEAD;            dst = xb + (size_t)row * DHEAD; }
  else { int r2 = row - NB * T1; src = y + (size_t)r2 * DHEAD;   dst = yb + (size_t)r2 * DHEAD; }
  float v = src[lane];
  float s = v * v;
  #pragma unroll
  for (int off = 32; off > 0; off >>= 1) s += __shfl_xor(s, off);
  float rn = 1.0f / fmaxf(sqrtf(s), 1e-12f);
  float o = v * rn;
  unsigned u = __float_as_uint(o);
  unsigned r = (u + 0x7fffu + ((u >> 16) & 1u)) >> 16;   // RNE to bf16
  dst[lane] = (ushort)r;
}

// ---------------- kernel 2: MFMA bf16 GEMM -> W[p][b][j][i] = exp(-(1-dot)) f16 ----------------
// LDS-staged epilogue (round 16, proven).
__global__ __launch_bounds__(256) void k_gemm_w(const ushort* __restrict__ xb,
                                                const ushort* __restrict__ yb,
                                                __half* __restrict__ W) {
  __shared__ __attribute__((aligned(16))) __half blk[128][132];   // 33792 B
  int pb = blockIdx.z;            // 0..95
  int p  = pb >> 5;               // 0:xy 1:xx 2:yy
  int b  = pb & 31;
  const ushort* A  = ((p == 2) ? yb : xb) + (size_t)b * T1 * DHEAD;  // i-side (M)
  const ushort* Bm = ((p == 1) ? xb : yb) + (size_t)b * T1 * DHEAD;  // j-side (N)

  int wid = threadIdx.x >> 6, lane = threadIdx.x & 63;
  int wm = wid >> 1, wn = wid & 1;
  int i0b = blockIdx.x * 128, j0b = blockIdx.y * 128;
  int i0 = i0b + wm * 64;
  int j0 = j0b + wn * 64;
  int lr = lane & 15, kg = lane >> 4;

  f32x4 acc[4][4];
  #pragma unroll
  for (int ic = 0; ic < 4; ++ic)
    #pragma unroll
    for (int jc = 0; jc < 4; ++jc) acc[ic][jc] = (f32x4){0.f, 0.f, 0.f, 0.f};

  #pragma unroll
  for (int kk = 0; kk < 2; ++kk) {
    int ko = kk * 32 + kg * 8;
    bf16x8 af[4], bf[4];
    #pragma unroll
    for (int ic = 0; ic < 4; ++ic)
      af[ic] = *reinterpret_cast<const bf16x8*>(A + (size_t)(i0 + ic * 16 + lr) * DHEAD + ko);
    #pragma unroll
    for (int jc = 0; jc < 4; ++jc)
      bf[jc] = *reinterpret_cast<const bf16x8*>(Bm + (size_t)(j0 + jc * 16 + lr) * DHEAD + ko);
    #pragma unroll
    for (int ic = 0; ic < 4; ++ic)
      #pragma unroll
      for (int jc = 0; jc < 4; ++jc)
        acc[ic][jc] = __builtin_amdgcn_mfma_f32_16x16x32_bf16(af[ic], bf[jc], acc[ic][jc], 0, 0, 0);
  }

  const float NLOG2E = -1.44269504088896340736f;
  #pragma unroll
  for (int ic = 0; ic < 4; ++ic) {
    int il = wm * 64 + ic * 16 + (kg << 2);
    #pragma unroll
    for (int jc = 0; jc < 4; ++jc) {
      int jl = wn * 64 + jc * 16 + lr;
      union { __half h[4]; uint2 u; } pk;
      #pragma unroll
      for (int r = 0; r < 4; ++r) {
        float d = 1.0f - acc[ic][jc][r];
        pk.h[r] = __float2half(exp2f(NLOG2E * d));
      }
      *reinterpret_cast<uint2*>(&blk[jl][il]) = pk.u;
    }
  }
  __syncthreads();

  __half* Wp = W + (size_t)pb * (T1 * T1);
  int tr = threadIdx.x >> 4;
  int tc = threadIdx.x & 15;
  #pragma unroll
  for (int q = 0; q < 8; ++q) {
    int j = q * 16 + tr;
    u32x4 v = *reinterpret_cast<const u32x4*>(&blk[j][tc << 3]);
    *reinterpret_cast<u32x4*>(Wp + (size_t)(j0b + j) * T1 + i0b + (tc << 3)) = v;
  }
}

// ---------------- kernel 3: soft-DTW, exp domain, skew-2, TWO columns per step ----------
// Lane l owns DP rows 8l+1..8l+8; at step tau processes cols c0=2(tau-l), c1=c0+1
// (320 steps, 40 groups of 8). One DPP cluster / guard / refill / producer round per
// step amortized over 2 cols. Neighbor feeds (lane l-1): up1 = live Va[7] end tau-1;
// up0 = diag1 = m7 (mid-step capture, after its col0 of tau-1); diag0 = d7 (live end
// tau-2). Renorm at KK7 (every 16 cols — same cadence as r17 -> values bit-identical).
// Base scales hoisted per group; at KK0, m7/d7 predate the renorm -> sDg0; live -> sUp.
// Ring: 152 slots (1KB cols), PFD=30, vmcnt(14) per 4 steps (landed cols <= 2tau+15 =
// exactly what the 8-col-ahead refills touch; waited loads are ~7.5 steps old >> HBM).
// WAR: slot of col c rewritten at step c/2+61 > last ds_read of col c at c/2+59.
// Guards: groups tau<64 (pre-active lanes would read unwritten ring slots) + final
// group (protects lane63's state at tau=319); middle unguarded (1-step safety: lane
// l+1's last active step l+256 reads lane l's end-of-(l+255) = its last active value).
// Readout: lane63 last active tau=318 (c1=511), state ends in Va -> Va[7].
__global__ __launch_bounds__(64, 1) void k_dtw(const __half* __restrict__ W,
                                               float* __restrict__ res) {
  __shared__ __attribute__((aligned(16))) char ring[RBYTES];
  const int prob = blockIdx.x;
  const __half* Wp = W + (size_t)prob * (T1 * T1);
  const int lane = threadIdx.x;

  float Va[8], Vb[8];
  #pragma unroll
  for (int r = 0; r < 8; ++r) { Va[r] = 0.f; Vb[r] = 0.f; }
  float B2 = 0.f, B2p = 0.f;
  float m7 = 0.f, d7 = 0.f;                 // mid-step / delayed V[7] captures
  const float dgSeed = (lane == 0) ? 1.0f : 0.0f;

  auto dppshr = [](float v) -> float {   // lane l <- lane l-1; lane 0 <- 0 (VALU only)
    return __int_as_float(__builtin_amdgcn_update_dpp(
        0, __float_as_int(v), 0x138 /*wave_shr:1*/, 0xF, 0xF, true));
  };

#define SCALEBITS(dexp) __uint_as_float( \
    (unsigned)(127 + (int)fminf(fmaxf((dexp), -120.f), 120.f)) << 23)

#define GLL16(GP, LP) __builtin_amdgcn_global_load_lds( \
    (const __attribute__((address_space(1))) void*)(GP), \
    (__attribute__((address_space(3))) void*)(LP), 16, 0, 0)

  const char* gW = (const char*)Wp;
  const unsigned laneOff = (unsigned)(lane << 4);   // 16 B/lane slice of a column

  // prologue: issue cols 0..29
  #pragma unroll
  for (int c = 0; c < PFD; ++c)
    GLL16(gW + ((size_t)c << 10) + laneOff, ring + ((unsigned)(c << 10)));
  asm volatile("s_waitcnt vmcnt(22)" ::: "memory");   // cols 0..7 landed

  // 8 buffers = 8 cols (4-step lead); dK holds col (K - 2*lane) initially.
  u32x4 d0, d1, d2, d3, d4, d5, d6, d7b;
  unsigned va0, va1, va2, va3, va4, va5, va6, va7;
#define RS_INIT(K, DN) do { \
    int n_ = (K) - 2 * lane; unsigned s_ = (unsigned)(n_ < 0 ? n_ + RSLOTS : n_); \
    DN = *reinterpret_cast<const u32x4*>(ring + (s_ << 10) + laneOff); \
    int m_ = n_ + 8; unsigned sm_ = (unsigned)(m_ < 0 ? m_ + RSLOTS : m_); \
    va##K = (sm_ << 10) + laneOff; \
  } while (0)
  RS_INIT(0, d0); RS_INIT(1, d1); RS_INIT(2, d2); RS_INIT(3, d3);
  RS_INIT(4, d4); RS_INIT(5, d5); RS_INIT(6, d6); RS_INIT(7, d7b);
#undef RS_INIT

  // producer: uniform column counters + ring byte offsets (wrap at RBYTES)
  unsigned colA = PFD, colB = PFD + 1;                // even / odd streams
  unsigned slA = (unsigned)(PFD << 10);
  unsigned slB = (unsigned)((PFD + 1) << 10);

#define DTW_STEP2(KK, DA, DB, SM, SD, SEEDK, GUARD) do {                      \
    const int t_ = tb + (KK);                                                 \
    float nbLive_ = dppshr(Va[7]);           /* nb end of t-1  -> up1 */      \
    float nbMid_  = dppshr(m7);              /* nb mid of t-1  -> up0,dg1 */  \
    float nbDel_  = dppshr(d7);              /* nb end of t-2  -> dg0 */      \
    d7 = Va[7];                              /* capture (pre-update) */       \
    float up0_ = nbMid_ * (SM);                                               \
    float dg0_ = nbDel_ * (SD);                                               \
    float up1_ = nbLive_ * sUp;                                               \
    if (SEEDK) dg0_ = dgSeed;                /* E[0][0]=1 enters col 0 only */\
    union { u32x4 u; __half h[8]; } cA_; cA_.u = DA;                          \
    union { u32x4 u; __half h[8]; } cB_; cB_.u = DB;                          \
    float wA_[8], wB_[8];                                                     \
    _Pragma("unroll")                                                         \
    for (int r = 0; r < 8; ++r) { wA_[r] = __half2float(cA_.h[r]);            \
                                  wB_[r] = __half2float(cB_.h[r]); }          \
    DA = *reinterpret_cast<const u32x4*>(ring + va##KK##A_IDX);               \
    va##KK##A_IDX += 8192u; if (va##KK##A_IDX >= RBYTES) va##KK##A_IDX -= RBYTES; \
    DB = *reinterpret_cast<const u32x4*>(ring + va##KK##B_IDX);               \
    va##KK##B_IDX += 8192u; if (va##KK##B_IDX >= RBYTES) va##KK##B_IDX -= RBYTES; \
    { unsigned cAc_ = colA > 511u ? 511u : colA;                              \
      unsigned cBc_ = colB > 511u ? 511u : colB;                              \
      GLL16(gW + ((size_t)cAc_ << 10) + laneOff, ring + slA);                 \
      GLL16(gW + ((size_t)cBc_ << 10) + laneOff, ring + slB);                 \
      colA += 2u; colB += 2u;                                                 \
      slA += 2048u; if (slA >= RBYTES) slA -= RBYTES;                         \
      slB += 2048u; if (slB >= RBYTES) slB -= RBYTES; }                       \
    bool act_ = true;                                                         \
    if (GUARD) { unsigned u_ = (unsigned)(t_ - lane); act_ = (u_ <= 255u); }  \
    if (act_) {                                                               \
      float c_ = fmaf(wA_[0], up0_, wA_[0] * (dg0_ + Va[0]));  Vb[0] = c_;    \
      _Pragma("unroll")                                                       \
      for (int r = 1; r < 8; ++r) {                                           \
        c_ = fmaf(wA_[r], c_, wA_[r] * (Va[r-1] + Va[r]));  Vb[r] = c_;       \
      }                                                                       \
      m7 = Vb[7];                            /* mid capture (pre-renorm) */   \
      c_ = fmaf(wB_[0], up1_, wB_[0] * (up0_ + Vb[0]));  Va[0] = c_;          \
      _Pragma("unroll")                                                       \
      for (int r = 1; r < 8; ++r) {                                           \
        c_ = fmaf(wB_[r], c_, wB_[r] * (Vb[r-1] + Vb[r]));  Va[r] = c_;       \
      }                                                                       \
      if ((KK) == 7) {                       /* exact pow2 renorm, 16 cols */ \
        float mx_ = fmaxf(fmaxf(fmaxf(Va[0],Va[1]),fmaxf(Va[2],Va[3])),       \
                          fmaxf(fmaxf(Va[4],Va[5]),fmaxf(Va[6],Va[7])));      \
        int e_ = (int)((__float_as_uint(mx_) >> 23) & 0xFF) - 127;            \
        e_ = e_ < -126 ? -126 : (e_ > 126 ? 126 : e_);                        \
        float sc_ = __uint_as_float((unsigned)(127 - e_) << 23);              \
        _Pragma("unroll")                                                     \
        for (int r = 0; r < 8; ++r) Va[r] *= sc_;                             \
        B2p = B2; B2 -= (float)e_;                                            \
      }                                                                       \
    }                                                                         \
  } while (0)

// buffer index aliases per KK (static): KK&3 selects the d-pair
#define va0A_IDX va0
#define va0B_IDX va1
#define va1A_IDX va2
#define va1B_IDX va3
#define va2A_IDX va4
#define va2B_IDX va5
#define va3A_IDX va6
#define va3B_IDX va7
#define va4A_IDX va0
#define va4B_IDX va1
#define va5A_IDX va2
#define va5B_IDX va3
#define va6A_IDX va4
#define va6B_IDX va5
#define va7A_IDX va6
#define va7B_IDX va7

#define DTW_GROUP2(GUARD, SEED) do {                                          \
    asm volatile("s_waitcnt vmcnt(14)" ::: "memory");  /* cols <= 2tb+15 */   \
    float nbBn_ = dppshr(B2);                                                 \
    float nbBo_ = dppshr(B2p);                                                \
    float sUp  = SCALEBITS(B2 - nbBn_);                                       \
    float sDg0 = SCALEBITS(B2 - nbBo_);                                       \
    DTW_STEP2(0, d0,  d1,  sDg0, sDg0, SEED,  GUARD);                         \
    DTW_STEP2(1, d2,  d3,  sUp,  sUp,  false, GUARD);                         \
    DTW_STEP2(2, d4,  d5,  sUp,  sUp,  false, GUARD);                         \
    DTW_STEP2(3, d6,  d7b, sUp,  sUp,  false, GUARD);                         \
    asm volatile("s_waitcnt vmcnt(14)" ::: "memory");  /* cols <= 2tb+23 */   \
    DTW_STEP2(4, d0,  d1,  sUp,  sUp,  false, GUARD);                         \
    DTW_STEP2(5, d2,  d3,  sUp,  sUp,  false, GUARD);                         \
    DTW_STEP2(6, d4,  d5,  sUp,  sUp,  false, GUARD);                         \
    DTW_STEP2(7, d6,  d7b, sUp,  sUp,  false, GUARD);                         \
  } while (0)

  // 40 groups of 8 steps = 320 steps (tau 0..319; lane63 last active tau=318).
  { const int tb = 0; DTW_GROUP2(true, true); }
  #pragma unroll 1
  for (int tb = 8; tb < 64; tb += 8)    DTW_GROUP2(true,  false);  // head era
  #pragma unroll 1
  for (int tb = 64; tb < 312; tb += 8)  DTW_GROUP2(false, false);  // unguarded
  { const int tb = 312; DTW_GROUP2(true, false); }                 // final group

  if (lane == 63) {
    // lane63 last active tau=318: c1=511 -> state in Va; col 511 = R[512][512].
    res[prob] = (B2 - log2f(Va[7])) * 0.69314718055994530942f;
  }
#undef DTW_STEP2
#undef DTW_GROUP2
#undef SCALEBITS
#undef GLL16
}

// ---------------- kernel 4: combine ----------------
__global__ void k_combine(const float* __restrict__ res, float* __restrict__ out) {
  int b = threadIdx.x;
  if (b < NB) out[b] = res[b] - 0.5f * (res[NB + b] + res[2 * NB + b]);
}

extern "C" void kernel_launch(void* const* d_in, const int* in_sizes, int n_in,
                              void* d_out, int out_size, void* d_ws, size_t ws_size,
                              hipStream_t stream) {
  const float* x = (const float*)d_in[0];
  const float* y = (const float*)d_in[1];
  float* out = (float*)d_out;

  const size_t xb_off  = 0;
  const size_t yb_off  = (size_t)NB * T1 * DHEAD * sizeof(ushort);           // 2 MB
  const size_t W_off   = 2 * yb_off;                                          // 4 MB
  const size_t res_off = W_off + (size_t)3 * NB * T1 * T1 * sizeof(__half);   // +50.33 MB
  const size_t need    = res_off + NP * sizeof(float);

  if (ws_size < need) {
    hipMemsetAsync(d_out, 0xFF, (size_t)out_size * sizeof(float), stream);
    return;
  }

  ushort* xb  = (ushort*)((char*)d_ws + xb_off);
  ushort* yb  = (ushort*)((char*)d_ws + yb_off);
  __half* W   = (__half*)((char*)d_ws + W_off);
  float*  res = (float*)((char*)d_ws + res_off);

  hipLaunchKernelGGL(k_normalize, dim3(8192), dim3(256), 0, stream, x, y, xb, yb);
  hipLaunchKernelGGL(k_gemm_w, dim3(4, 4, 96), dim3(256), 0, stream, xb, yb, W);
  hipLaunchKernelGGL(k_dtw, dim3(NP), dim3(64), 0, stream, W, res);
  hipLaunchKernelGGL(k_combine, dim3(1), dim3(64), 0, stream, res, out);
}